// Round 8
// baseline (165.880 us; speedup 1.0000x reference)
//
#include <hip/hip_runtime.h>
#include <hip/hip_bf16.h>
#include <stdint.h>

#define B_DIM 32
#define I_DIM 2048
#define J_DIM 2048
#define K_DIM 128

typedef __attribute__((ext_vector_type(8))) short bf16x8;
typedef __attribute__((ext_vector_type(4))) float f32x4;

// pack 8 fp32 (k-ascending) -> bf16x8 via v_cvt_pk_bf16_f32 (RNE)
__device__ inline bf16x8 pack8(const f32x4 lo, const f32x4 hi) {
  union { __hip_bfloat162 h2[4]; bf16x8 v; } u;
  u.h2[0] = __float22bfloat162_rn(make_float2(lo[0], lo[1]));
  u.h2[1] = __float22bfloat162_rn(make_float2(lo[2], lo[3]));
  u.h2[2] = __float22bfloat162_rn(make_float2(hi[0], hi[1]));
  u.h2[3] = __float22bfloat162_rn(make_float2(hi[2], hi[3]));
  return u.v;
}

#define GLD_LDS16(gp, lp) __builtin_amdgcn_global_load_lds( \
    (const __attribute__((address_space(1))) uint32_t*)(gp), \
    (__attribute__((address_space(3))) uint32_t*)(lp), 16, 0, 0)

// Single-pass direct-fp32 BMM. 128x128 tile, BK=32 (4 chunks), 4 waves.
// LDS 32KB: A fp32 [128 i][32 k] (rows 128B, slot^=(i&7) swizzle, via
// pre-swizzled global source); B fp32 [32 k][128 j] (rows 512B, j-slots
// rotated by 4*(k>>3) so column reads are 2-way-bank = free).
__global__ __launch_bounds__(256, 3) void bmm_direct(const float* __restrict__ A,
                                                     const float* __restrict__ B,
                                                     float* __restrict__ C) {
  __shared__ __align__(16) char lds[32768];
  const int t = threadIdx.x;
  const int p = blockIdx.x;
  const int jt = p & 15, it = (p >> 4) & 15, b = p >> 8;

  const int w = t >> 6, wm = w >> 1, wn = w & 1;
  const int lane = t & 63, lr = lane & 15, g = lane >> 4;
  const int h = lr & 7;

  // ---- staging addresses ----
  // A: inst q covers LDS rows q*32..q*32+31; thread t -> row ar=t>>3, slot as=t&7.
  const int ar = t >> 3, as = t & 7;
  const float* Asrc = A + ((size_t)b * I_DIM + it * 128 + ar) * K_DIM
                        + ((as ^ (ar & 7)) << 2);           // pre-swizzled slot
  // B: inst q covers k-rows q*8..q*8+7; thread t -> row br=t>>5, slot bs=t&31.
  const int br = t >> 5, bs = t & 31;
  const float* Bsrc = B + (size_t)b * K_DIM * J_DIM + (size_t)br * J_DIM + jt * 128;
  char* AdstW = lds + w * 1024;            // + q*4096; HW adds lane*16
  char* BdstW = lds + 16384 + w * 1024;

  f32x4 acc[4][4];
  #pragma unroll
  for (int m = 0; m < 4; ++m)
    #pragma unroll
    for (int n = 0; n < 4; ++n)
      acc[m][n] = (f32x4){0.f, 0.f, 0.f, 0.f};

  #pragma unroll
  for (int ki = 0; ki < 4; ++ki) {         // K = 4 x BK=32
    if (ki) __syncthreads();               // LDS reads of prev chunk done
    #pragma unroll
    for (int q = 0; q < 4; ++q) {
      GLD_LDS16(Asrc + (size_t)q * 32 * K_DIM + ki * 32, AdstW + q * 4096);
      GLD_LDS16(Bsrc + (size_t)(ki * 32 + q * 8) * J_DIM + (((bs - 4 * q) & 31) << 2),
                BdstW + q * 4096);
    }
    __syncthreads();                       // compiler drains vmcnt before barrier

    bf16x8 af[4], bb[4];
    #pragma unroll
    for (int m = 0; m < 4; ++m) {          // A frags: 2x b128 + cvt
      const char* row = lds + (wm * 64 + m * 16 + lr) * 128;
      const f32x4 lo = *reinterpret_cast<const f32x4*>(row + (((2 * g)     ^ h) << 4));
      const f32x4 hi = *reinterpret_cast<const f32x4*>(row + (((2 * g + 1) ^ h) << 4));
      af[m] = pack8(lo, hi);
    }
    #pragma unroll
    for (int n = 0; n < 4; ++n) {          // B frags: 8x b32 column read (rotated)
      const int j = wn * 64 + n * 16 + lr;
      f32x4 lo, hi;
      #pragma unroll
      for (int e = 0; e < 4; ++e)
        lo[e] = *reinterpret_cast<const float*>(
            lds + 16384 + (g * 8 + e) * 512 + (((j + 16 * g) & 127) << 2));
      #pragma unroll
      for (int e = 0; e < 4; ++e)
        hi[e] = *reinterpret_cast<const float*>(
            lds + 16384 + (g * 8 + 4 + e) * 512 + (((j + 16 * g) & 127) << 2));
      bb[n] = pack8(lo, hi);
    }
    #pragma unroll
    for (int m = 0; m < 4; ++m)
      #pragma unroll
      for (int n = 0; n < 4; ++n)
        acc[m][n] = __builtin_amdgcn_mfma_f32_16x16x32_bf16(af[m], bb[n], acc[m][n], 0, 0, 0);
  }

  // ---- C write: col = lane&15, row = g*4 + reg (verified layout) ----
  float* Cb = C + (size_t)b * I_DIM * J_DIM;
  const int cbase = jt * 128 + wn * 64 + lr;
  #pragma unroll
  for (int m = 0; m < 4; ++m) {
    const int rbase = it * 128 + wm * 64 + m * 16 + g * 4;
    #pragma unroll
    for (int q = 0; q < 4; ++q) {
      float* crow = Cb + (size_t)(rbase + q) * J_DIM + cbase;
      #pragma unroll
      for (int n = 0; n < 4; ++n) crow[n * 16] = acc[m][n][q];
    }
  }
}

extern "C" void kernel_launch(void* const* d_in, const int* in_sizes, int n_in,
                              void* d_out, int out_size, void* d_ws, size_t ws_size,
                              hipStream_t stream) {
  const float* A = (const float*)d_in[0];
  const float* B = (const float*)d_in[1];
  float* C = (float*)d_out;
  bmm_direct<<<8192, 256, 0, stream>>>(A, B, C);
}

// Round 9
// 157.318 us; speedup vs baseline: 1.0544x; 1.0544x over previous
//
#include <hip/hip_runtime.h>
#include <hip/hip_bf16.h>
#include <stdint.h>

#define B_DIM 32
#define I_DIM 2048
#define J_DIM 2048
#define K_DIM 128

typedef __attribute__((ext_vector_type(8))) short bf16x8;
typedef __attribute__((ext_vector_type(4))) short short4v;
typedef __attribute__((ext_vector_type(4))) float f32x4;
typedef __attribute__((ext_vector_type(16))) float f32x16;

__device__ inline short f2bf(float f) {
  union { float f; uint32_t u; } v; v.f = f;
  uint32_t u = v.u + 0x7fffu + ((v.u >> 16) & 1u);  // RNE
  return (short)(u >> 16);
}

// ---------------- pass 1a: A fp32 [b][i][k] -> bf16 (same layout) ----------------
__global__ __launch_bounds__(256) void convA_kernel(const float* __restrict__ A,
                                                    short* __restrict__ Ab) {
  const int idx = blockIdx.x * 256 + threadIdx.x;     // 8 elements each
  const f32x4* p = reinterpret_cast<const f32x4*>(A) + (size_t)idx * 2;
  const f32x4 a = p[0], b = p[1];
  bf16x8 o;
  o[0] = f2bf(a[0]); o[1] = f2bf(a[1]); o[2] = f2bf(a[2]); o[3] = f2bf(a[3]);
  o[4] = f2bf(b[0]); o[5] = f2bf(b[1]); o[6] = f2bf(b[2]); o[7] = f2bf(b[3]);
  reinterpret_cast<bf16x8*>(Ab)[idx] = o;
}

// ---------------- pass 1b: B fp32 [b][k][j] -> Bt bf16 [b][j][k] ----------------
// float4 global reads (full 1KB/inst coalescing); LDS tile swizzled as before.
__global__ __launch_bounds__(256) void transB_kernel(const float* __restrict__ B,
                                                     short* __restrict__ Bt) {
  __shared__ __align__(16) short tile[64 * 128];
  const int t  = threadIdx.x;
  const int j0 = blockIdx.x * 64;
  const int b  = blockIdx.y;
  const float* Bb = B + (size_t)b * K_DIM * J_DIM;
  const int qj = t & 15;          // j-quad within 64
  const int k0 = t >> 4;          // 0..15
  #pragma unroll
  for (int kp = 0; kp < 8; ++kp) {
    const int k = kp * 16 + k0;
    const f32x4 v = *reinterpret_cast<const f32x4*>(Bb + (size_t)k * J_DIM + j0 + 4 * qj);
    #pragma unroll
    for (int e = 0; e < 4; ++e) {
      const int jj = 4 * qj + e;
      tile[jj * 128 + (k ^ ((jj & 15) << 3))] = f2bf(v[e]);
    }
  }
  __syncthreads();
  short* Btb = Bt + (size_t)b * J_DIM * K_DIM;
  const int slot = t & 15, jr = t >> 4;
  #pragma unroll
  for (int r2 = 0; r2 < 4; ++r2) {
    const int j  = r2 * 16 + jr;
    const bf16x8 v = *reinterpret_cast<const bf16x8*>(&tile[j * 128 + slot * 8]);
    const int kk0 = (slot * 8) ^ ((j & 15) << 3);
    *reinterpret_cast<bf16x8*>(Btb + (size_t)(j0 + j) * K_DIM + kk0) = v;
  }
}

// ---------------- pass 2: bf16 GEMM, 128x128 tile, BK=64, 32x32x16 MFMA ----------------
// Same staging/LDS as R3; MFMA shape switched to 32x32x16 so each C-store
// instruction writes 2 x 128B FULL-LINE segments (col = lane&31).
#define GLD_LDS16(g, l) __builtin_amdgcn_global_load_lds( \
    (const __attribute__((address_space(1))) uint32_t*)(g), \
    (__attribute__((address_space(3))) uint32_t*)(l), 16, 0, 0)

__global__ __launch_bounds__(256, 4) void gemm_kernel(const short* __restrict__ Ab,
                                                      const short* __restrict__ Bt,
                                                      float* __restrict__ C) {
  __shared__ __align__(16) short As[8192];   // [128 r][64 k] bf16, slot^(r&7) swizzle
  __shared__ __align__(16) short Bs[8192];
  const int t = threadIdx.x;
  const int p = blockIdx.x;
  const int jt = p & 15, it = (p >> 4) & 15, b = p >> 8;

  const int rsub  = t >> 3;                                   // 0..31
  const int kbyte = ((t & 7) << 4) ^ ((rsub & 7) << 4);       // pre-swizzled source
  const char* Asrc = (const char*)(Ab + (size_t)(b * I_DIM + it * 128 + rsub) * K_DIM) + kbyte;
  const char* Bsrc = (const char*)(Bt + (size_t)(b * J_DIM + jt * 128 + rsub) * K_DIM) + kbyte;
  char* Adst = (char*)As + (t >> 6) * 1024;   // wave-uniform base; HW adds lane*16
  char* Bdst = (char*)Bs + (t >> 6) * 1024;

  const int w  = t >> 6, wm = w >> 1, wn = w & 1;
  const int l  = t & 63;
  const int lr32 = l & 31;        // MFMA row/col within 32
  const int g2   = l >> 5;        // k-half selector

  f32x16 acc[2][2];
  #pragma unroll
  for (int m = 0; m < 2; ++m)
    #pragma unroll
    for (int n = 0; n < 2; ++n)
      #pragma unroll
      for (int e = 0; e < 16; ++e) acc[m][n][e] = 0.f;

  #pragma unroll
  for (int ki = 0; ki < 2; ++ki) {            // K = 2 x BK=64
    if (ki) __syncthreads();                  // LDS reads of prev chunk done
    #pragma unroll
    for (int q = 0; q < 4; ++q) {
      GLD_LDS16(Asrc + q * 8192 + ki * 128, Adst + q * 4096);
      GLD_LDS16(Bsrc + q * 8192 + ki * 128, Bdst + q * 4096);
    }
    __syncthreads();                          // vmcnt drained by compiler
    #pragma unroll
    for (int kq = 0; kq < 4; ++kq) {          // 4 x K=16 MFMA steps
      const int s = kq * 2 + g2;              // 16B slot within 128B row
      bf16x8 af[2], bb[2];
      #pragma unroll
      for (int m = 0; m < 2; ++m) {
        const int R = wm * 64 + m * 32 + lr32;
        af[m] = *reinterpret_cast<const bf16x8*>((const char*)As + R * 128 + ((s ^ (R & 7)) << 4));
      }
      #pragma unroll
      for (int n = 0; n < 2; ++n) {
        const int R = wn * 64 + n * 32 + lr32;
        bb[n] = *reinterpret_cast<const bf16x8*>((const char*)Bs + R * 128 + ((s ^ (R & 7)) << 4));
      }
      #pragma unroll
      for (int m = 0; m < 2; ++m)
        #pragma unroll
        for (int n = 0; n < 2; ++n)
          acc[m][n] = __builtin_amdgcn_mfma_f32_32x32x16_bf16(af[m], bb[n], acc[m][n], 0, 0, 0);
    }
  }

  // ---- C write: col = lane&31, row = (r&3) + 8*(r>>2) + 4*(lane>>5) ----
  // Each store inst: 2 x 128B contiguous full-line segments.
  float* Cb = C + (size_t)b * I_DIM * J_DIM;
  #pragma unroll
  for (int m = 0; m < 2; ++m) {
    const int rowbase = it * 128 + wm * 64 + m * 32 + 4 * g2;
    #pragma unroll
    for (int n = 0; n < 2; ++n) {
      const int colbase = jt * 128 + wn * 64 + n * 32 + lr32;
      #pragma unroll
      for (int r = 0; r < 16; ++r) {
        const int row = rowbase + (r & 3) + 8 * (r >> 2);
        Cb[(size_t)row * J_DIM + colbase] = acc[m][n][r];
      }
    }
  }
}

// ---------------- fallback (used only if ws too small) ----------------
__device__ inline int swz_fb(int row, int kbyte) {
  return row * 128 + ((kbyte ^ ((row & 15) << 4)) >> 1);
}

__global__ __launch_bounds__(256, 2) void bmm_fallback(const float* __restrict__ A,
                                                       const float* __restrict__ Bm,
                                                       float* __restrict__ C) {
  __shared__ short As[128 * 128];
  __shared__ short Bs[128 * 128];
  const int t  = threadIdx.x;
  const int jt = blockIdx.x, it = blockIdx.y, b = blockIdx.z;
  const float* Abp = A  + (size_t)b * I_DIM * K_DIM;
  const float* Bbp = Bm + (size_t)b * K_DIM * J_DIM;
  {
    const int r0 = t >> 5;
    const int k0 = (t & 31) * 4;
    #pragma unroll 4
    for (int i8 = 0; i8 < 16; ++i8) {
      const int r = i8 * 8 + r0;
      const float4 v = *reinterpret_cast<const float4*>(
          Abp + (size_t)(it * 128 + r) * K_DIM + k0);
      short4v s; s.x = f2bf(v.x); s.y = f2bf(v.y); s.z = f2bf(v.z); s.w = f2bf(v.w);
      *reinterpret_cast<short4v*>(&As[swz_fb(r, 2 * k0)]) = s;
    }
  }
  {
    const int j  = t & 127;
    const int kq = (t >> 7) * 4;
    #pragma unroll 4
    for (int kb = 0; kb < 16; ++kb) {
      const int k0 = kb * 8 + kq;
      const float* p = Bbp + (size_t)k0 * J_DIM + jt * 128 + j;
      const float f0 = p[0], f1 = p[J_DIM], f2 = p[2 * J_DIM], f3 = p[3 * J_DIM];
      short4v s; s.x = f2bf(f0); s.y = f2bf(f1); s.z = f2bf(f2); s.w = f2bf(f3);
      *reinterpret_cast<short4v*>(&Bs[swz_fb(j, 2 * k0)]) = s;
    }
  }
  __syncthreads();
  const int w = t >> 6, wm = w >> 1, wn = w & 1;
  const int lane = t & 63, lr = lane & 15, g = lane >> 4;
  f32x4 acc[4][4];
  #pragma unroll
  for (int m = 0; m < 4; ++m)
    #pragma unroll
    for (int n = 0; n < 4; ++n) acc[m][n] = (f32x4){0.f, 0.f, 0.f, 0.f};
  #pragma unroll
  for (int kk = 0; kk < 4; ++kk) {
    bf16x8 af[4], bfr[4];
    const int kb = kk * 64 + g * 16;
    #pragma unroll
    for (int m = 0; m < 4; ++m) {
      const int r = wm * 64 + m * 16 + lr;
      af[m] = *reinterpret_cast<const bf16x8*>(&As[swz_fb(r, kb)]);
    }
    #pragma unroll
    for (int n = 0; n < 4; ++n) {
      const int r = wn * 64 + n * 16 + lr;
      bfr[n] = *reinterpret_cast<const bf16x8*>(&Bs[swz_fb(r, kb)]);
    }
    #pragma unroll
    for (int m = 0; m < 4; ++m)
      #pragma unroll
      for (int n = 0; n < 4; ++n)
        acc[m][n] = __builtin_amdgcn_mfma_f32_16x16x32_bf16(af[m], bfr[n], acc[m][n], 0, 0, 0);
  }
  float* Cb = C + (size_t)b * I_DIM * J_DIM;
  const int cbase = jt * 128 + wn * 64 + lr;
  #pragma unroll
  for (int m = 0; m < 4; ++m) {
    const int rbase = it * 128 + wm * 64 + m * 16 + g * 4;
    #pragma unroll
    for (int q = 0; q < 4; ++q) {
      float* crow = Cb + (size_t)(rbase + q) * J_DIM + cbase;
      #pragma unroll
      for (int n = 0; n < 4; ++n) crow[n * 16] = acc[m][n][q];
    }
  }
}

extern "C" void kernel_launch(void* const* d_in, const int* in_sizes, int n_in,
                              void* d_out, int out_size, void* d_ws, size_t ws_size,
                              hipStream_t stream) {
  const float* A  = (const float*)d_in[0];
  const float* Bm = (const float*)d_in[1];
  float* C = (float*)d_out;
  const size_t needA = (size_t)B_DIM * I_DIM * K_DIM * sizeof(short);  // 16 MiB
  const size_t needB = (size_t)B_DIM * K_DIM * J_DIM * sizeof(short);  // 16 MiB
  if (ws_size >= needA + needB) {
    short* Ab = (short*)d_ws;
    short* Bt = (short*)((char*)d_ws + needA);
    convA_kernel<<<4096, 256, 0, stream>>>(A, Ab);
    transB_kernel<<<dim3(J_DIM / 64, B_DIM), 256, 0, stream>>>(Bm, Bt);
    gemm_kernel<<<8192, 256, 0, stream>>>(Ab, Bt, C);
  } else {
    bmm_fallback<<<dim3(J_DIM / 128, I_DIM / 128, B_DIM), 256, 0, stream>>>(A, Bm, C);
  }
}

// Round 10
// 139.663 us; speedup vs baseline: 1.1877x; 1.1264x over previous
//
#include <hip/hip_runtime.h>
#include <hip/hip_bf16.h>
#include <stdint.h>

#define B_DIM 32
#define I_DIM 2048
#define J_DIM 2048
#define K_DIM 128

typedef __attribute__((ext_vector_type(8))) short bf16x8;
typedef __attribute__((ext_vector_type(4))) short short4v;
typedef __attribute__((ext_vector_type(4))) float f32x4;

__device__ inline short f2bf(float f) {
  union { float f; uint32_t u; } v; v.f = f;
  uint32_t u = v.u + 0x7fffu + ((v.u >> 16) & 1u);  // RNE
  return (short)(u >> 16);
}

// ---------------- pass 1a: A fp32 [b][i][k] -> bf16 (same layout) ----------------
__global__ __launch_bounds__(256) void convA_kernel(const float* __restrict__ A,
                                                    short* __restrict__ Ab) {
  const int idx = blockIdx.x * 256 + threadIdx.x;     // 8 elements each
  const float4* p = reinterpret_cast<const float4*>(A) + (size_t)idx * 2;
  const float4 a = p[0], b = p[1];
  bf16x8 o;
  o[0] = f2bf(a.x); o[1] = f2bf(a.y); o[2] = f2bf(a.z); o[3] = f2bf(a.w);
  o[4] = f2bf(b.x); o[5] = f2bf(b.y); o[6] = f2bf(b.z); o[7] = f2bf(b.w);
  reinterpret_cast<bf16x8*>(Ab)[idx] = o;
}

// ---------------- pass 1b: B fp32 [b][k][j] -> Bt bf16 [b][j][k] ----------------
__global__ __launch_bounds__(256) void transB_kernel(const float* __restrict__ B,
                                                     short* __restrict__ Bt) {
  __shared__ __align__(16) short tile[64 * 128];
  const int t  = threadIdx.x;
  const int j0 = blockIdx.x * 64;
  const int b  = blockIdx.y;
  const float* Bb = B + (size_t)b * K_DIM * J_DIM;
  const int jj = t & 63, kq = t >> 6;
  #pragma unroll
  for (int kr = 0; kr < 32; ++kr) {
    const int k = kr * 4 + kq;
    const float v = Bb[(size_t)k * J_DIM + j0 + jj];
    tile[jj * 128 + (k ^ ((jj & 15) << 3))] = f2bf(v);
  }
  __syncthreads();
  short* Btb = Bt + (size_t)b * J_DIM * K_DIM;
  const int slot = t & 15, jr = t >> 4;
  #pragma unroll
  for (int r2 = 0; r2 < 4; ++r2) {
    const int j  = r2 * 16 + jr;
    const bf16x8 v = *reinterpret_cast<const bf16x8*>(&tile[j * 128 + slot * 8]);
    const int k0 = (slot * 8) ^ ((j & 15) << 3);
    *reinterpret_cast<bf16x8*>(Btb + (size_t)(j0 + j) * K_DIM + k0) = v;
  }
}

// ---------------- pass 2: persistent 4-tile GEMM, counted-vmcnt pipeline ----------------
// Block = (b, it, jg): four 128x128 tiles at jt = jg*4+q. A tile (32KB bf16) staged
// once; per tile only B restaged. Raw s_barrier + s_waitcnt vmcnt(63): the 8 staging
// loads are OLDER than the 64 just-issued C stores, so vmcnt(63) drains the loads
// while leaving stores in flight -> HBM write stream stays busy across tiles.
// LDS element (row r, 16B slot s_l) holds global k-slot s_l ^ (r&15); frag reads
// use slot s ^ lr -> quarter-wave conflict-free.
#define GLD_LDS16(g, l) __builtin_amdgcn_global_load_lds( \
    (const __attribute__((address_space(1))) uint32_t*)(g), \
    (__attribute__((address_space(3))) uint32_t*)(l), 16, 0, 0)

__global__ __launch_bounds__(256, 2) void gemm_kernel(const short* __restrict__ Ab,
                                                      const short* __restrict__ Bt,
                                                      float* __restrict__ C) {
  __shared__ __align__(16) short As[128 * 128];   // 32 KB, whole K
  __shared__ __align__(16) short Bs[128 * 128];   // 32 KB, whole K
  const int t = threadIdx.x;
  const int p = blockIdx.x;
  const int jg = p & 3, it = (p >> 2) & 15, b = p >> 6;

  const int w = t >> 6, wm = w >> 1, wn = w & 1;
  const int lane = t & 63, lr = lane & 15, g = lane >> 4;

  // staging: inst i covers rows 16i..16i+15; thread t -> row t>>4, dest slot t&15,
  // source slot (t&15)^(row&15)  (pre-swizzled global source, rule 21)
  const int srow  = t >> 4;                       // 0..15
  const int sbyte = ((t & 15) ^ srow) << 4;
  const char* Asrc  = (const char*)(Ab + ((size_t)b * I_DIM + it * 128 + srow) * K_DIM) + sbyte;
  const char* Bbase = (const char*)(Bt + ((size_t)b * J_DIM + srow) * K_DIM) + sbyte;
  char* Adst = (char*)As + w * 1024;              // wave-uniform base; HW adds lane*16
  char* Bdst = (char*)Bs + w * 1024;

  // ---- prologue: stage A (full) + B tile jg*4 ----
  #pragma unroll
  for (int i = 0; i < 8; ++i) GLD_LDS16(Asrc + i * 4096, Adst + i * 4096);
  {
    const char* Bsrc = Bbase + (size_t)(jg * 4) * 128 * 256;
    #pragma unroll
    for (int i = 0; i < 8; ++i) GLD_LDS16(Bsrc + i * 4096, Bdst + i * 4096);
  }
  asm volatile("s_waitcnt vmcnt(0)" ::: "memory");
  __builtin_amdgcn_sched_barrier(0);
  __builtin_amdgcn_s_barrier();
  __builtin_amdgcn_sched_barrier(0);

  float* Cb = C + (size_t)b * I_DIM * J_DIM;

  #pragma unroll
  for (int q = 0; q < 4; ++q) {
    const int jt = jg * 4 + q;

    f32x4 acc[4][4];
    #pragma unroll
    for (int m = 0; m < 4; ++m)
      #pragma unroll
      for (int n = 0; n < 4; ++n)
        acc[m][n] = (f32x4){0.f, 0.f, 0.f, 0.f};

    #pragma unroll
    for (int kg = 0; kg < 4; ++kg) {            // K = 4 x 32
      const int sl = kg * 4 + g;                // global k-slot (16B units)
      bf16x8 af[4], bb[4];
      #pragma unroll
      for (int m = 0; m < 4; ++m) {
        const int R = wm * 64 + m * 16 + lr;
        af[m] = *reinterpret_cast<const bf16x8*>((const char*)As + R * 256 + ((sl ^ lr) << 4));
      }
      #pragma unroll
      for (int n = 0; n < 4; ++n) {
        const int R = wn * 64 + n * 16 + lr;
        bb[n] = *reinterpret_cast<const bf16x8*>((const char*)Bs + R * 256 + ((sl ^ lr) << 4));
      }
      #pragma unroll
      for (int m = 0; m < 4; ++m)
        #pragma unroll
        for (int n = 0; n < 4; ++n)
          acc[m][n] = __builtin_amdgcn_mfma_f32_16x16x32_bf16(af[m], bb[n], acc[m][n], 0, 0, 0);
    }

    // all waves' LDS reads consumed (compiler lgkmcnt before each MFMA) -> Bs free
    __builtin_amdgcn_s_barrier();
    __builtin_amdgcn_sched_barrier(0);

    if (q < 3) {                                // stage next B (8 loads, oldest in queue)
      const char* Bsrc = Bbase + (size_t)(jt + 1) * 128 * 256;
      #pragma unroll
      for (int i = 0; i < 8; ++i) GLD_LDS16(Bsrc + i * 4096, Bdst + i * 4096);
    }

    // issue C stores for tile q (fire-and-forget; drain overlaps next tile)
    const int cbase = jt * 128 + wn * 64 + lr;
    #pragma unroll
    for (int m = 0; m < 4; ++m) {
      const int rbase = it * 128 + wm * 64 + m * 16 + g * 4;
      #pragma unroll
      for (int qq = 0; qq < 4; ++qq) {
        float* crow = Cb + (size_t)(rbase + qq) * J_DIM + cbase;
        #pragma unroll
        for (int n = 0; n < 4; ++n) crow[n * 16] = acc[m][n][qq];
      }
    }

    if (q < 3) {
      // loads are older than the 64 new stores: vmcnt(63) guarantees loads landed
      // while leaving ~63 stores in flight.
      asm volatile("s_waitcnt vmcnt(63)" ::: "memory");
      __builtin_amdgcn_sched_barrier(0);
      __builtin_amdgcn_s_barrier();
      __builtin_amdgcn_sched_barrier(0);
    }
  }
}

// ---------------- fallback (used only if ws too small) ----------------
__device__ inline int swz_fb(int row, int kbyte) {
  return row * 128 + ((kbyte ^ ((row & 15) << 4)) >> 1);
}

__global__ __launch_bounds__(256, 2) void bmm_fallback(const float* __restrict__ A,
                                                       const float* __restrict__ Bm,
                                                       float* __restrict__ C) {
  __shared__ short As[128 * 128];
  __shared__ short Bs[128 * 128];
  const int t  = threadIdx.x;
  const int jt = blockIdx.x, it = blockIdx.y, b = blockIdx.z;
  const float* Abp = A  + (size_t)b * I_DIM * K_DIM;
  const float* Bbp = Bm + (size_t)b * K_DIM * J_DIM;
  {
    const int r0 = t >> 5;
    const int k0 = (t & 31) * 4;
    #pragma unroll 4
    for (int i8 = 0; i8 < 16; ++i8) {
      const int r = i8 * 8 + r0;
      const float4 v = *reinterpret_cast<const float4*>(
          Abp + (size_t)(it * 128 + r) * K_DIM + k0);
      short4v s; s.x = f2bf(v.x); s.y = f2bf(v.y); s.z = f2bf(v.z); s.w = f2bf(v.w);
      *reinterpret_cast<short4v*>(&As[swz_fb(r, 2 * k0)]) = s;
    }
  }
  {
    const int j  = t & 127;
    const int kq = (t >> 7) * 4;
    #pragma unroll 4
    for (int kb = 0; kb < 16; ++kb) {
      const int k0 = kb * 8 + kq;
      const float* p = Bbp + (size_t)k0 * J_DIM + jt * 128 + j;
      const float f0 = p[0], f1 = p[J_DIM], f2 = p[2 * J_DIM], f3 = p[3 * J_DIM];
      short4v s; s.x = f2bf(f0); s.y = f2bf(f1); s.z = f2bf(f2); s.w = f2bf(f3);
      *reinterpret_cast<short4v*>(&Bs[swz_fb(j, 2 * k0)]) = s;
    }
  }
  __syncthreads();
  const int w = t >> 6, wm = w >> 1, wn = w & 1;
  const int lane = t & 63, lr = lane & 15, g = lane >> 4;
  f32x4 acc[4][4];
  #pragma unroll
  for (int m = 0; m < 4; ++m)
    #pragma unroll
    for (int n = 0; n < 4; ++n) acc[m][n] = (f32x4){0.f, 0.f, 0.f, 0.f};
  #pragma unroll
  for (int kk = 0; kk < 4; ++kk) {
    bf16x8 af[4], bfr[4];
    const int kb = kk * 64 + g * 16;
    #pragma unroll
    for (int m = 0; m < 4; ++m) {
      const int r = wm * 64 + m * 16 + lr;
      af[m] = *reinterpret_cast<const bf16x8*>(&As[swz_fb(r, kb)]);
    }
    #pragma unroll
    for (int n = 0; n < 4; ++n) {
      const int r = wn * 64 + n * 16 + lr;
      bfr[n] = *reinterpret_cast<const bf16x8*>(&Bs[swz_fb(r, kb)]);
    }
    #pragma unroll
    for (int m = 0; m < 4; ++m)
      #pragma unroll
      for (int n = 0; n < 4; ++n)
        acc[m][n] = __builtin_amdgcn_mfma_f32_16x16x32_bf16(af[m], bfr[n], acc[m][n], 0, 0, 0);
  }
  float* Cb = C + (size_t)b * I_DIM * J_DIM;
  const int cbase = jt * 128 + wn * 64 + lr;
  #pragma unroll
  for (int m = 0; m < 4; ++m) {
    const int rbase = it * 128 + wm * 64 + m * 16 + g * 4;
    #pragma unroll
    for (int q = 0; q < 4; ++q) {
      float* crow = Cb + (size_t)(rbase + q) * J_DIM + cbase;
      #pragma unroll
      for (int n = 0; n < 4; ++n) crow[n * 16] = acc[m][n][q];
    }
  }
}

extern "C" void kernel_launch(void* const* d_in, const int* in_sizes, int n_in,
                              void* d_out, int out_size, void* d_ws, size_t ws_size,
                              hipStream_t stream) {
  const float* A  = (const float*)d_in[0];
  const float* Bm = (const float*)d_in[1];
  float* C = (float*)d_out;
  const size_t needA = (size_t)B_DIM * I_DIM * K_DIM * sizeof(short);  // 16 MiB
  const size_t needB = (size_t)B_DIM * K_DIM * J_DIM * sizeof(short);  // 16 MiB
  if (ws_size >= needA + needB) {
    short* Ab = (short*)d_ws;
    short* Bt = (short*)((char*)d_ws + needA);
    convA_kernel<<<4096, 256, 0, stream>>>(A, Ab);
    transB_kernel<<<dim3(J_DIM / 64, B_DIM), 256, 0, stream>>>(Bm, Bt);
    gemm_kernel<<<2048, 256, 0, stream>>>(Ab, Bt, C);   // 32b x 16it x 4jg
  } else {
    bmm_fallback<<<dim3(J_DIM / 128, I_DIM / 128, B_DIM), 256, 0, stream>>>(A, Bm, C);
  }
}